// Round 2
// baseline (181.970 us; speedup 1.0000x reference)
//
#include <hip/hip_runtime.h>
#include <hip/hip_bf16.h>
#include <math.h>

// BlockSparseAttention: x[1,4096,1024] fp32; w_qkv[3072,1024], b_qkv[3072],
// w_out[1024,1024], b_out[1024] fp32. out[4096,1024] fp32.
// blocks of 128; global blocks {0,24}; qb attends {0,qb,24} (or all if qb global).

#define SEQ 4096
#define DIM 1024
#define NHEADS 16
#define HDIM 64
#define BS 128

using short8 = __attribute__((ext_vector_type(8))) short;   // 8 x bf16 bits
using floatx4 = __attribute__((ext_vector_type(4))) float;

__device__ __forceinline__ float bf2f(short s) {
  unsigned u = ((unsigned)(unsigned short)s) << 16;
  return __uint_as_float(u);
}

__device__ __forceinline__ unsigned pack_bf16(float a, float b) {
  __hip_bfloat16 ba = __float2bfloat16(a);
  __hip_bfloat16 bb = __float2bfloat16(b);
  return ((unsigned)*(unsigned short*)&bb << 16) | (unsigned)*(unsigned short*)&ba;
}

__device__ __forceinline__ void gld_lds16(const __hip_bfloat16* g, __hip_bfloat16* l) {
  // 16B per lane, dest = wave-uniform base + lane*16 [guide §5, m97/m104]
  __builtin_amdgcn_global_load_lds(
      (const __attribute__((address_space(1))) unsigned int*)g,
      (__attribute__((address_space(3))) unsigned int*)l, 16, 0, 0);
}

// ---------------------------------------------------------------------------
// merged fp32 -> bf16 downcast for x (4096 blks), w_qkv (3072), w_out (1024)
// ---------------------------------------------------------------------------
__global__ __launch_bounds__(256) void downcast3(
    const float* __restrict__ x, const float* __restrict__ wq,
    const float* __restrict__ wo, __hip_bfloat16* __restrict__ xd,
    __hip_bfloat16* __restrict__ wqd, __hip_bfloat16* __restrict__ wod) {
  int id = blockIdx.x;
  const float* src;
  __hip_bfloat16* dst;
  int base;
  if (id < 4096) { src = x; dst = xd; base = id; }
  else if (id < 7168) { src = wq; dst = wqd; base = id - 4096; }
  else { src = wo; dst = wod; base = id - 7168; }
  int i = (base * 256 + threadIdx.x) * 4;
  float4 v = *(const float4*)(src + i);
  __hip_bfloat16 b0 = __float2bfloat16(v.x);
  __hip_bfloat16 b1 = __float2bfloat16(v.y);
  __hip_bfloat16 b2 = __float2bfloat16(v.z);
  __hip_bfloat16 b3 = __float2bfloat16(v.w);
  ushort4 packed = {*(unsigned short*)&b0, *(unsigned short*)&b1,
                    *(unsigned short*)&b2, *(unsigned short*)&b3};
  *(ushort4*)(((unsigned short*)dst) + i) = packed;
}

// ---------------------------------------------------------------------------
// QKV GEMM, 256^2-tile 8-wave 8-phase schedule (T2+T3+T4+T5 per guide §5).
// M=4096, N=3072, K=1024 -> grid 16x12=192 wgs, 512 threads (2Mx4N waves).
// LDS 128KB: A[2dbuf][256][64]bf16 + B[2dbuf][256][64]bf16, XOR-swizzled
// ((row&7)<<4) with inverse swizzle on the per-lane GLOBAL source (rule #21:
// global_load_lds dest stays linear). Per K-tile: 4 phases snaking quadrants
// (m0n0, m0n1, m1n1, m1n0); prefetch stream per tile t: B1(t+1)@p1,
// B0(t+2)@p3, A0+A1(t+2)@p4; boundary s_waitcnt vmcnt(6) (never 0 mid-loop)
// guarantees tile t+1 landed with 3 half-tiles (6 loads) in flight.
// Raw s_barrier + memory-clobber asm so the compiler can't re-insert the
// vmcnt(0) drain that caps the m97 structure at ~37% MfmaUtil.
// NOTE: no local arrays of LDS-derived pointers (hipcc 'static initializer
// addrspacecast' error) — all LDS bases computed as arithmetic on pool.
// Operand swap kept: Q/K slabs compute with A=weights (fr-dim = output row ->
// coalesced row-major store); V slab swapped -> Vt.
// ---------------------------------------------------------------------------
#define NT 16  // K-tiles of 64

__global__ __launch_bounds__(512, 2) void gemm_qkv(const __hip_bfloat16* __restrict__ Amat,
                                                   const __hip_bfloat16* __restrict__ Wmat,
                                                   const float* __restrict__ Bias,
                                                   __hip_bfloat16* __restrict__ qkv) {
  __shared__ __align__(16) char pool[131072];
  const int t = threadIdx.x;
  const int w = t >> 6;
  const int lane = t & 63;
  const int fr = lane & 15;
  const int quad = lane >> 4;
  const int wA = w >> 2;        // A-operand half (0..1)
  const int wB = w & 3;         // B-operand quarter (0..3)
  const int bro = (wB & 1) * 64;  // B row offset within its half

  int id = blockIdx.x;                     // 192 wgs, 192%8==0 -> simple XCD swizzle
  int swz = (id & 7) * 24 + (id >> 3);
  int m_idx = swz & 15;                    // 0..15
  int n_idx = swz >> 4;                    // 0..11
  const int m0 = m_idx * 256;
  const int n0 = n_idx * 256;
  const int s = n0 >> 10;                  // 0:Q 1:K 2:V
  const int cc0 = n0 & 1023;
  const bool vmode = (s == 2);

  // A-operand rows (fr-dim of C = B rows; quad-dim = A rows)
  const __hip_bfloat16* APtr = vmode ? Amat + (size_t)m0 * DIM : Wmat + (size_t)n0 * DIM;
  const __hip_bfloat16* BPtr = vmode ? Wmat + (size_t)n0 * DIM : Amat + (size_t)m0 * DIM;

  // LDS layout (bytes): A slot0 [0,32K), A slot1 [32K,64K),
  //                     B slot0 [64K,96K), B slot1 [96K,128K).
  // Each slot: half h at +h*16384 (128 rows x 128B).

  // Stage one half-tile (128 rows x 64 cols bf16 = 16KB): 2 gld_lds16/thread.
  // LDS dest linear; global source pre-permuted by the read-side XOR swizzle.
  auto STG = [&](int kt, int ab, int h) {
    const __hip_bfloat16* rowbase = (ab ? BPtr : APtr) + (size_t)(h * 128) * DIM;
    char* lb = pool + ab * 65536 + (kt & 1) * 32768 + h * 16384;
#pragma unroll
    for (int c = 0; c < 2; ++c) {
      int r = c * 64 + (t >> 3);           // row within half-tile
      int g = t & 7;                       // physical 16B granule
      gld_lds16(rowbase + (size_t)r * DIM + kt * 64 + ((g ^ (r & 7)) << 3),
                (__hip_bfloat16*)(lb + (c * 512 + w * 64) * 16));
    }
  };

  // Swizzled fragment read: row-local-to-half, kk in {0,1} selects K-slice.
  auto frag = [&](const char* base, int row, int kk) -> short8 {
    return *(const short8*)(base + row * 128 +
                            ((kk * 64 + quad * 16) ^ ((row & 7) << 4)));
  };

#define SBAR()                            \
  do {                                    \
    asm volatile("" ::: "memory");        \
    __builtin_amdgcn_s_barrier();         \
    asm volatile("" ::: "memory");        \
  } while (0)

  // ---- prologue: tile0 {A0,A1,B0,B1}, tile1 {A0,A1,B0}; B1(1) comes @p1(0)
  STG(0, 0, 0); STG(0, 0, 1); STG(0, 1, 0); STG(0, 1, 1);
  STG(1, 0, 0); STG(1, 0, 1); STG(1, 1, 0);
  asm volatile("s_waitcnt vmcnt(6)" ::: "memory");  // tile0 landed
  __builtin_amdgcn_s_barrier();
  asm volatile("" ::: "memory");

  floatx4 acc[8][4];
#pragma unroll
  for (int i = 0; i < 8; ++i)
#pragma unroll
    for (int j = 0; j < 4; ++j) acc[i][j] = (floatx4){0.f, 0.f, 0.f, 0.f};

  for (int kt = 0; kt < NT; ++kt) {
    const int d = kt & 1;
    const char* Al = pool + d * 32768 + wA * 16384;
    const char* Bl = pool + 65536 + d * 32768 + (wB >> 1) * 16384;
    short8 af[4][2], bf0[2][2], bf1[2][2];

    // ---- phase 1: quadrant (m0, n0) ----
#pragma unroll
    for (int at = 0; at < 4; ++at) {
      af[at][0] = frag(Al, at * 16 + fr, 0);
      af[at][1] = frag(Al, at * 16 + fr, 1);
    }
#pragma unroll
    for (int bt = 0; bt < 2; ++bt) {
      bf0[bt][0] = frag(Bl, bro + bt * 16 + fr, 0);
      bf0[bt][1] = frag(Bl, bro + bt * 16 + fr, 1);
    }
    if (kt < NT - 1) STG(kt + 1, 1, 1);   // B1(t+1) -> other slot
    __builtin_amdgcn_s_setprio(1);
#pragma unroll
    for (int at = 0; at < 4; ++at)
#pragma unroll
      for (int bt = 0; bt < 2; ++bt) {
        acc[at][bt] = __builtin_amdgcn_mfma_f32_16x16x32_bf16(af[at][0], bf0[bt][0], acc[at][bt], 0, 0, 0);
        acc[at][bt] = __builtin_amdgcn_mfma_f32_16x16x32_bf16(af[at][1], bf0[bt][1], acc[at][bt], 0, 0, 0);
      }
    __builtin_amdgcn_s_setprio(0);
    SBAR();

    // ---- phase 2: quadrant (m0, n1) ----
#pragma unroll
    for (int bt = 0; bt < 2; ++bt) {
      bf1[bt][0] = frag(Bl, bro + (bt + 2) * 16 + fr, 0);
      bf1[bt][1] = frag(Bl, bro + (bt + 2) * 16 + fr, 1);
    }
    __builtin_amdgcn_s_setprio(1);
#pragma unroll
    for (int at = 0; at < 4; ++at)
#pragma unroll
      for (int bt = 0; bt < 2; ++bt) {
        acc[at][bt + 2] = __builtin_amdgcn_mfma_f32_16x16x32_bf16(af[at][0], bf1[bt][0], acc[at][bt + 2], 0, 0, 0);
        acc[at][bt + 2] = __builtin_amdgcn_mfma_f32_16x16x32_bf16(af[at][1], bf1[bt][1], acc[at][bt + 2], 0, 0, 0);
      }
    __builtin_amdgcn_s_setprio(0);
    SBAR();  // all B reads of tile t done -> B region of slot d reusable

    // ---- phase 3: quadrant (m1, n1) ----
#pragma unroll
    for (int at = 0; at < 4; ++at) {
      af[at][0] = frag(Al, (at + 4) * 16 + fr, 0);
      af[at][1] = frag(Al, (at + 4) * 16 + fr, 1);
    }
    if (kt < NT - 2) STG(kt + 2, 1, 0);   // B0(t+2) -> slot d (B free)
    __builtin_amdgcn_s_setprio(1);
#pragma unroll
    for (int at = 0; at < 4; ++at)
#pragma unroll
      for (int bt = 0; bt < 2; ++bt) {
        acc[at + 4][bt + 2] = __builtin_amdgcn_mfma_f32_16x16x32_bf16(af[at][0], bf1[bt][0], acc[at + 4][bt + 2], 0, 0, 0);
        acc[at + 4][bt + 2] = __builtin_amdgcn_mfma_f32_16x16x32_bf16(af[at][1], bf1[bt][1], acc[at + 4][bt + 2], 0, 0, 0);
      }
    __builtin_amdgcn_s_setprio(0);
    SBAR();  // all A reads of tile t done -> A region of slot d reusable

    // ---- phase 4: quadrant (m1, n0), bf0 held in regs ----
    if (kt < NT - 2) { STG(kt + 2, 0, 0); STG(kt + 2, 0, 1); }  // A0,A1(t+2)
    __builtin_amdgcn_s_setprio(1);
#pragma unroll
    for (int at = 0; at < 4; ++at)
#pragma unroll
      for (int bt = 0; bt < 2; ++bt) {
        acc[at + 4][bt] = __builtin_amdgcn_mfma_f32_16x16x32_bf16(af[at][0], bf0[bt][0], acc[at + 4][bt], 0, 0, 0);
        acc[at + 4][bt] = __builtin_amdgcn_mfma_f32_16x16x32_bf16(af[at][1], bf0[bt][1], acc[at + 4][bt], 0, 0, 0);
      }
    __builtin_amdgcn_s_setprio(0);

    // ---- tile boundary: tile t+1 fully landed, 3 half-tiles in flight ----
    if (kt < NT - 2) asm volatile("s_waitcnt vmcnt(6)" ::: "memory");
    else             asm volatile("s_waitcnt vmcnt(0)" ::: "memory");
    __builtin_amdgcn_s_barrier();
    asm volatile("" ::: "memory");
  }

  // ---- epilogue: stage C (bf16) into swizzled Ep[256 F][256 Q] = 128KB ----
  // F = B-operand-local row (fr-dim), Q = A-operand-local row (quad-dim).
#pragma unroll
  for (int at = 0; at < 8; ++at)
#pragma unroll
    for (int bt = 0; bt < 4; ++bt) {
      int F = wB * 64 + bt * 16 + fr;
      int q0b = (wA * 128 + at * 16 + quad * 4) * 2;  // byte offset along Q
      ushort4 pk;
      unsigned short* pks = (unsigned short*)&pk;
#pragma unroll
      for (int i = 0; i < 4; ++i) {
        __hip_bfloat16 bb = __float2bfloat16(acc[at][bt][i]);
        pks[i] = *(unsigned short*)&bb;
      }
      *(ushort4*)(pool + F * 512 + (q0b ^ ((F & 7) << 4))) = pk;
    }
  __syncthreads();

  {
    int F = t >> 1;          // output row index within tile (along fr-dim)
    int hh = t & 1;          // which 128-elem half of the 256-wide row
    if (!vmode) {
      // F = m-local, Q = n-local. Row-major Q/K store.
      __hip_bfloat16* drow = qkv + (size_t)s * SEQ * DIM + (size_t)(m0 + F) * DIM + cc0;
#pragma unroll
      for (int g16 = 0; g16 < 16; ++g16) {
        int G = hh * 16 + g16;
        short8 v8 = *(const short8*)(pool + F * 512 + ((G << 4) ^ ((F & 7) << 4)));
        float4 b0 = *(const float4*)&Bias[n0 + G * 8];
        float4 b1 = *(const float4*)&Bias[n0 + G * 8 + 4];
        float bbv[8] = {b0.x, b0.y, b0.z, b0.w, b1.x, b1.y, b1.z, b1.w};
        short8 o8;
#pragma unroll
        for (int k = 0; k < 8; ++k) {
          __hip_bfloat16 ob = __float2bfloat16(bf2f(v8[k]) + bbv[k]);
          o8[k] = *(short*)&ob;
        }
        *(short8*)&drow[G * 8] = o8;
      }
    } else {
      // F = n-local (weight row), Q = m-local. Store transposed into Vt.
      __hip_bfloat16* vt = qkv + 2ull * SEQ * DIM;
      __hip_bfloat16* drow = vt + (size_t)(cc0 + F) * SEQ + m0;
      float bv = Bias[n0 + F];
#pragma unroll
      for (int g16 = 0; g16 < 16; ++g16) {
        int G = hh * 16 + g16;
        short8 v8 = *(const short8*)(pool + F * 512 + ((G << 4) ^ ((F & 7) << 4)));
        short8 o8;
#pragma unroll
        for (int k = 0; k < 8; ++k) {
          __hip_bfloat16 ob = __float2bfloat16(bf2f(v8[k]) + bv);
          o8[k] = *(short*)&ob;
        }
        *(short8*)&drow[G * 8] = o8;
      }
    }
  }
#undef SBAR
}

// ---------------------------------------------------------------------------
// out-proj GEMM: 128x64 tiles -> 512 wgs (2/CU) for latency overlap.
// ---------------------------------------------------------------------------
__global__ __launch_bounds__(256) void gemm_out(const __hip_bfloat16* __restrict__ Amat,
                                                const __hip_bfloat16* __restrict__ Wmat,
                                                const float* __restrict__ Bias,
                                                float* __restrict__ out) {
  __shared__ __align__(16) __hip_bfloat16 Asmem[128 * 32];
  __shared__ __align__(16) __hip_bfloat16 Bsmem[64 * 32];
  const int Kd = DIM;
  const int t = threadIdx.x;
  const int w = t >> 6;
  const int lane = t & 63;
  const int fr = lane & 15;
  const int quad = lane >> 4;
  const int wm = w >> 1, wn = w & 1;
  int id = blockIdx.x;
  int xcd = id & 7, j = id >> 3;       // j in [0,64)
  int m_idx = xcd + (j & 3) * 8;       // 0..31
  int n_idx = j >> 2;                  // 0..15
  const int m0 = m_idx * 128;
  const int n0 = n_idx * 64;
  const __hip_bfloat16* Ablk = Amat + (size_t)m0 * Kd;
  const __hip_bfloat16* Bblk = Wmat + (size_t)n0 * Kd;
  floatx4 acc[4][2];
#pragma unroll
  for (int i = 0; i < 4; ++i)
#pragma unroll
    for (int jj = 0; jj < 2; ++jj) acc[i][jj] = (floatx4){0.f, 0.f, 0.f, 0.f};
  for (int kk = 0; kk < Kd / 32; ++kk) {
#pragma unroll
    for (int jj = 0; jj < 2; ++jj) {
      int c = jj * 256 + t;
      int ldso = (jj * 256 + w * 64) * 8;
      gld_lds16(Ablk + (size_t)(c >> 2) * Kd + kk * 32 + (c & 3) * 8, &Asmem[ldso]);
    }
    gld_lds16(Bblk + (size_t)(t >> 2) * Kd + kk * 32 + (t & 3) * 8, &Bsmem[t * 8]);
    __syncthreads();
    short8 af[4], bf_[2];
#pragma unroll
    for (int mt = 0; mt < 4; ++mt)
      af[mt] = *(const short8*)&Asmem[(wm * 64 + mt * 16 + fr) * 32 + quad * 8];
#pragma unroll
    for (int nt = 0; nt < 2; ++nt)
      bf_[nt] = *(const short8*)&Bsmem[(wn * 32 + nt * 16 + fr) * 32 + quad * 8];
#pragma unroll
    for (int mt = 0; mt < 4; ++mt)
#pragma unroll
      for (int nt = 0; nt < 2; ++nt)
        acc[mt][nt] = __builtin_amdgcn_mfma_f32_16x16x32_bf16(af[mt], bf_[nt],
                                                              acc[mt][nt], 0, 0, 0);
    __syncthreads();
  }
#pragma unroll
  for (int nt = 0; nt < 2; ++nt) {
    int n = n0 + wn * 32 + nt * 16 + fr;
    float bv = Bias[n];
#pragma unroll
    for (int mt = 0; mt < 4; ++mt) {
      int m = m0 + wm * 64 + mt * 16 + quad * 4;
#pragma unroll
      for (int i = 0; i < 4; ++i)
        out[(size_t)(m + i) * DIM + n] = acc[mt][nt][i] + bv;
    }
  }
}

// ---------------------------------------------------------------------------
// MFMA flash attention, S^T formulation.
// St = K.Q^T: lane holds St[key=nt*16+quad*4+i][row=fr] -> lane-local softmax.
// P repack to PV B-operand via shuffle: dest lane (quad,fr), chunk ks2, word p
// needs pki[2*ks2 + (quad>>1)][p&1] from lane fr+16*(2*(quad&1)+(p>>1)).
// FIX vs round 8: nt-select (quad>>1) is DESTINATION-dependent, so shuffle
// BOTH candidates and select after (sel-before-shfl evaluated on src lane).
// PV: O^T = Vt.P^T; O^T C-layout -> contiguous stores. LDS = 32KB.
// ---------------------------------------------------------------------------
__global__ __launch_bounds__(256) void attn_mfma(
    const __hip_bfloat16* __restrict__ qkv,
    __hip_bfloat16* __restrict__ aout,
    float* __restrict__ po, float* __restrict__ pm, float* __restrict__ pl) {
  __shared__ __align__(16) __hip_bfloat16 Kbuf[16 * 512];    // 16KB, 16 frags
  __shared__ __align__(16) __hip_bfloat16 Vbuf[16 * 512];    // 16KB, 16 frags
  const int h = blockIdx.y;
  const int wgid = blockIdx.x;
  const int t = threadIdx.x;
  const int wv = t >> 6;
  const int lane = t & 63;
  const int fr = lane & 15;
  const int quad = lane >> 4;

  int qb, q0, niter, slice = 0, pid = 0;
  bool direct;
  if (wgid < 60) {
    int nb = wgid >> 1;                 // 0..29
    qb = (nb < 23) ? nb + 1 : nb + 2;   // 1..23, 25..31
    q0 = qb * BS + (wgid & 1) * 64;
    niter = 3;
    direct = true;
  } else {
    int gi = wgid - 60;                 // 0..31
    slice = gi & 7;
    int chunk = gi >> 3;                // 0..3
    qb = (chunk >> 1) * 24;             // 0 or 24
    q0 = qb * BS + (chunk & 1) * 64;
    niter = 4;
    direct = false;
    pid = (h * 4 + chunk) * 8 + slice;
  }

  const __hip_bfloat16* Q = qkv;
  const __hip_bfloat16* K = qkv + (size_t)SEQ * DIM;
  const __hip_bfloat16* Vt = qkv + 2ull * SEQ * DIM;  // [DIM][SEQ]

  // Q B-frags: lane holds Q[row=fr][dim=quad*8+j] (+32 for chunk 1)
  short8 qa0, qa1;
  {
    const __hip_bfloat16* qp =
        Q + (size_t)(q0 + wv * 16 + fr) * DIM + h * HDIM + quad * 8;
    qa0 = *(const short8*)(qp);
    qa1 = *(const short8*)(qp + 32);
  }

  float mrow = -INFINITY, lsum = 0.f;
  floatx4 o[4];
#pragma unroll
  for (int i = 0; i < 4; ++i) o[i] = (floatx4){0.f, 0.f, 0.f, 0.f};

  for (int bi = 0; bi < niter; ++bi) {
    int kb = direct ? (bi == 0 ? 0 : (bi == 1 ? qb : 24)) : slice * 4 + bi;

    // ---- cooperative frag-major staging of K and V tiles ----
    const __hip_bfloat16* Kg = K + (size_t)(kb * BS) * DIM + h * HDIM;
    const __hip_bfloat16* Vg = Vt + (size_t)(h * HDIM) * SEQ + kb * BS;
    __syncthreads();  // all waves done reading previous K/V tiles
#pragma unroll
    for (int rr = 0; rr < 4; ++rr) {
      int f = rr * 4 + wv;              // wave-uniform frag id
      int nt = f >> 1, ks = f & 1;      // K frag coords
      gld_lds16(Kg + (size_t)(nt * 16 + fr) * DIM + ks * 32 + quad * 8,
                &Kbuf[f * 512]);
      int nt2 = f >> 2, ks2 = f & 3;    // V frag coords
      gld_lds16(Vg + (size_t)(nt2 * 16 + fr) * SEQ + ks2 * 32 + quad * 8,
                &Vbuf[f * 512]);
    }
    __syncthreads();  // DMA drained

    // ---- St = K.Q^T: lane holds St[key=nt*16+quad*4+i][row=fr] ----
    floatx4 s[8];
#pragma unroll
    for (int nt = 0; nt < 8; ++nt) {
      short8 kf0 = *(const short8*)&Kbuf[(nt * 2 + 0) * 512 + lane * 8];
      short8 kf1 = *(const short8*)&Kbuf[(nt * 2 + 1) * 512 + lane * 8];
      floatx4 acc = {0.f, 0.f, 0.f, 0.f};
      acc = __builtin_amdgcn_mfma_f32_16x16x32_bf16(kf0, qa0, acc, 0, 0, 0);
      acc = __builtin_amdgcn_mfma_f32_16x16x32_bf16(kf1, qa1, acc, 0, 0, 0);
      s[nt] = acc;
    }
#pragma unroll
    for (int nt = 0; nt < 8; ++nt)
#pragma unroll
      for (int i = 0; i < 4; ++i) s[nt][i] *= 0.125f;

    // ---- lane-local online softmax (row = fr) ----
    float rmax = -INFINITY;
#pragma unroll
    for (int nt = 0; nt < 8; ++nt)
#pragma unroll
      for (int i = 0; i < 4; ++i) rmax = fmaxf(rmax, s[nt][i]);
    rmax = fmaxf(rmax, __shfl_xor(rmax, 16, 64));
    rmax = fmaxf(rmax, __shfl_xor(rmax, 32, 64));
    float newm = fmaxf(mrow, rmax);
    float alpha = __expf(mrow - newm);   // first iter: exp(-inf)=0
    float psum = 0.f;
    unsigned pki[8][2];
#pragma unroll
    for (int nt = 0; nt < 8; ++nt) {
      float p0 = __expf(s[nt][0] - newm);
      float p1 = __expf(s[nt][1] - newm);
      float p2 = __expf(s[nt][2] - newm);
      float p3 = __expf(s[nt][3] - newm);
      psum += (p0 + p1) + (p2 + p3);
      pki[nt][0] = pack_bf16(p0, p1);
      pki[nt][1] = pack_bf16(p2, p3);
    }
    psum += __shfl_xor(psum, 16, 64);
    psum += __shfl_xor(psum, 32, 64);
    lsum = lsum * alpha + psum;
    mrow = newm;
#pragma unroll
    for (int nt2 = 0; nt2 < 4; ++nt2)
#pragma unroll
      for (int i = 0; i < 4; ++i) o[nt2][i] *= alpha;

    // ---- in-register repack: P C-layout -> PV B-frags (select AFTER shfl) ----
    union { int w4[4]; short8 s8; } pw[4];
#pragma unroll
    for (int ks2 = 0; ks2 < 4; ++ks2) {
#pragma unroll
      for (int p = 0; p < 4; ++p) {
        int srcl = fr + ((((quad & 1) << 1) + (p >> 1)) << 4);
        int lo = __shfl((int)pki[2 * ks2][p & 1], srcl, 64);
        int hi = __shfl((int)pki[2 * ks2 + 1][p & 1], srcl, 64);
        pw[ks2].w4[p] = (quad & 2) ? hi : lo;
      }
    }

    // ---- PV: O^T += Vt . P^T ----
#pragma unroll
    for (int nt2 = 0; nt2 < 4; ++nt2) {
#pragma unroll
      for (int ks2 = 0; ks2 < 4; ++ks2) {
        short8 vb = *(const short8*)&Vbuf[(nt2 * 4 + ks2) * 512 + lane * 8];
        o[nt2] = __builtin_amdgcn_mfma_f32_16x16x32_bf16(vb, pw[ks2].s8, o[nt2], 0, 0, 0);
      }
    }
  }

  // O^T C-layout: lane holds O[row=fr][d = nt2*16 + quad*4 + i] -> contiguous
  if (direct) {
    float inv = 1.f / lsum;
    __hip_bfloat16* orow = aout + (size_t)(q0 + wv * 16 + fr) * DIM + h * HDIM + quad * 4;
#pragma unroll
    for (int nt2 = 0; nt2 < 4; ++nt2) {
      ushort4 pk;
      unsigned short* pks = (unsigned short*)&pk;
#pragma unroll
      for (int i = 0; i < 4; ++i) {
        __hip_bfloat16 ob = __float2bfloat16(o[nt2][i] * inv);
        pks[i] = *(unsigned short*)&ob;
      }
      *(ushort4*)(orow + nt2 * 16) = pk;
    }
  } else {
    float* pob = po + (size_t)pid * 4096 + (wv * 16 + fr) * 64 + quad * 4;
#pragma unroll
    for (int nt2 = 0; nt2 < 4; ++nt2) {
      float4 v = {o[nt2][0], o[nt2][1], o[nt2][2], o[nt2][3]};
      *(float4*)(pob + nt2 * 16) = v;
    }
    if (quad == 0) {
      pm[pid * 64 + wv * 16 + fr] = mrow;
      pl[pid * 64 + wv * 16 + fr] = lsum;
    }
  }
}

// ---------------------------------------------------------------------------
// Combine 8 KV-slice partials for the global q-blocks (unchanged).
// ---------------------------------------------------------------------------
__global__ __launch_bounds__(256) void combine(const float* __restrict__ po,
                                               const float* __restrict__ pm,
                                               const float* __restrict__ pl,
                                               __hip_bfloat16* __restrict__ aout) {
  int b = blockIdx.x;  // h*4 + chunk
  int h = b >> 2, chunk = b & 3;
  int t = threadIdx.x;
  int row = t >> 2;
  int d0 = (t & 3) * 16;

  float m8[8];
  float newm = -INFINITY;
#pragma unroll
  for (int s = 0; s < 8; ++s) {
    m8[s] = pm[(b * 8 + s) * 64 + row];
    newm = fmaxf(newm, m8[s]);
  }
  float wgt[8], lsum = 0.f;
#pragma unroll
  for (int s = 0; s < 8; ++s) {
    wgt[s] = __expf(m8[s] - newm);
    lsum += pl[(b * 8 + s) * 64 + row] * wgt[s];
  }
  float acc[16];
#pragma unroll
  for (int jj = 0; jj < 16; ++jj) acc[jj] = 0.f;
#pragma unroll
  for (int s = 0; s < 8; ++s) {
    const float* src = po + ((size_t)(b * 8 + s) * 4096) + row * 64 + d0;
#pragma unroll
    for (int j4 = 0; j4 < 4; ++j4) {
      float4 v = *(const float4*)(src + j4 * 4);
      acc[j4 * 4 + 0] += wgt[s] * v.x;
      acc[j4 * 4 + 1] += wgt[s] * v.y;
      acc[j4 * 4 + 2] += wgt[s] * v.z;
      acc[j4 * 4 + 3] += wgt[s] * v.w;
    }
  }
  float inv = 1.f / lsum;
  int qrow = (chunk >> 1) * 3072 + (chunk & 1) * 64 + row;
#pragma unroll
  for (int jj = 0; jj < 16; ++jj)
    aout[(size_t)qrow * DIM + h * HDIM + d0 + jj] = __float2bfloat16(acc[jj] * inv);
}

// ---------------------------------------------------------------------------
extern "C" void kernel_launch(void* const* d_in, const int* in_sizes, int n_in,
                              void* d_out, int out_size, void* d_ws, size_t ws_size,
                              hipStream_t stream) {
  const float* x = (const float*)d_in[0];
  const float* w_qkv = (const float*)d_in[1];
  const float* b_qkv = (const float*)d_in[2];
  const float* w_out = (const float*)d_in[3];
  const float* b_out = (const float*)d_in[4];
  float* out = (float*)d_out;

  // ws layout (bytes):
  //   [0,   24M) bf16 qkv: Q[SEQ][DIM], K[SEQ][DIM], Vt[DIM][SEQ]
  //   [24M, 32M) bf16 x_bf   -- dead after gemm_qkv; reused as po (8MB fp32)
  //   [32M, 38M) bf16 wqkv_bf -- dead after gemm_qkv; first 256KB reused as pm/pl
  //   [38M, 40M) bf16 wout_bf
  //   [40M, 48M) bf16 attn_ws [SEQ][DIM]
  char* wsb = (char*)d_ws;
  __hip_bfloat16* qkv_ws = (__hip_bfloat16*)(wsb);
  __hip_bfloat16* x_bf = (__hip_bfloat16*)(wsb + 24ull * 1024 * 1024);
  __hip_bfloat16* wqkv_bf = (__hip_bfloat16*)(wsb + 32ull * 1024 * 1024);
  __hip_bfloat16* wout_bf = (__hip_bfloat16*)(wsb + 38ull * 1024 * 1024);
  __hip_bfloat16* attn_ws = (__hip_bfloat16*)(wsb + 40ull * 1024 * 1024);
  float* po = (float*)(wsb + 24ull * 1024 * 1024);           // 512*64*64*4 = 8MB
  float* pm = (float*)(wsb + 32ull * 1024 * 1024);           // 128KB
  float* pl = (float*)(wsb + 32ull * 1024 * 1024 + 131072);  // 128KB

  dim3 blk(256);
  downcast3<<<dim3(8192), blk, 0, stream>>>(x, w_qkv, w_out, x_bf, wqkv_bf, wout_bf);
  gemm_qkv<<<dim3(192), dim3(512), 0, stream>>>(x_bf, wqkv_bf, b_qkv, qkv_ws);
  attn_mfma<<<dim3(92, NHEADS), blk, 0, stream>>>(qkv_ws, attn_ws, po, pm, pl);
  combine<<<dim3(64), blk, 0, stream>>>(po, pm, pl, attn_ws);
  gemm_out<<<dim3(512), blk, 0, stream>>>(attn_ws, wout_bf, b_out, out);
}